// Round 5
// baseline (231.731 us; speedup 1.0000x reference)
//
#include <hip/hip_runtime.h>
#include <math.h>

#define V 8192
#define D 128
#define NH 8
#define HD 16
#define SEQ 128
#define HID 341
#define EPS 1e-6f
#define NBLK 128
#define NTHR 512
#define POISONU 0xAAAAAAAAu

__device__ __forceinline__ float sigm(float x) { return 1.0f / (1.0f + __expf(-x)); }

struct SM {
    float ps[NH][SEQ + 2];
    float parts4[4][D];
    float pB[3][2][D];
    float qs[D], qrow[D], krow[D], orow[D], h2[D], xrow[D];
    float afA[HID], afB[HID], af[HID];
    float rl[NH];
    float scr[8];
};

// 512-thread block-wide sum (waves are 64 lanes; 8 wave-partials in scr).
__device__ __forceinline__ float block_sum512(float v, float* scr) {
    #pragma unroll
    for (int m = 32; m > 0; m >>= 1) v += __shfl_xor(v, m);
    if ((threadIdx.x & 63) == 0) scr[threadIdx.x >> 6] = v;
    __syncthreads();
    float s = ((scr[0] + scr[1]) + (scr[2] + scr[3])) + ((scr[4] + scr[5]) + (scr[6] + scr[7]));
    __syncthreads();
    return s;
}

// Grid-wide barrier: 128 co-resident blocks, generation counter in bar[1],
// arrival counter in bar[0] (reset before gen increment -> next-barrier safe).
__device__ __forceinline__ void grid_barrier(unsigned* bar, unsigned target) {
    __threadfence();
    __syncthreads();
    if (threadIdx.x == 0) {
        unsigned old = atomicAdd(&bar[0], 1u);
        if (old == (unsigned)(NBLK - 1)) {
            atomicExch(&bar[0], 0u);
            __threadfence();
            atomicAdd(&bar[1], 1u);
        }
        while (__hip_atomic_load(&bar[1], __ATOMIC_ACQUIRE, __HIP_MEMORY_SCOPE_AGENT) < target) {
            __builtin_amdgcn_s_sleep(2);
        }
    }
    __syncthreads();
    __threadfence();
}

// QKV (from normalized row in S.h2) + rope. 512 threads, dual-task split:
// t<128: q-h0 + k-h1 ; [128,256): k-h0 + v-h1 ; [256,384): v-h0 ; [384,512): q-h1.
__device__ __forceinline__ void qkv_rope_512(int s, int t, SM& S,
                                             const float* __restrict__ wq,
                                             const float* __restrict__ wk,
                                             const float* __restrict__ wv,
                                             float* __restrict__ koutg,
                                             float* __restrict__ voutg) {
    int col = t & 127;
    const float* h = S.h2;
    if (t < 256) {
        const float* Wa = (t < 128) ? wq : wk;
        const float* Wb = (t < 128) ? wk : wv;
        float a0 = 0, a1 = 0, b0 = 0, b1 = 0;
        #pragma unroll 8
        for (int u = 0; u < 64; u += 2) {
            a0 += h[u] * Wa[u * D + col];
            a1 += h[u + 1] * Wa[(u + 1) * D + col];
            b0 += h[64 + u] * Wb[(64 + u) * D + col];
            b1 += h[64 + u + 1] * Wb[(64 + u + 1) * D + col];
        }
        S.pB[(t < 128) ? 0 : 1][0][col] = a0 + a1;
        S.pB[(t < 128) ? 1 : 2][1][col] = b0 + b1;
    } else {
        const float* Wa = (t < 384) ? wv : wq;
        int dlo = (t < 384) ? 0 : 64;
        float a0 = 0, a1 = 0;
        #pragma unroll 8
        for (int u = 0; u < 64; u += 2) {
            a0 += h[dlo + u] * Wa[(dlo + u) * D + col];
            a1 += h[dlo + u + 1] * Wa[(dlo + u + 1) * D + col];
        }
        S.pB[(t < 384) ? 2 : 0][(t < 384) ? 0 : 1][col] = a0 + a1;
    }
    __syncthreads();
    if (t < 128) {
        float qv = S.pB[0][0][t] + S.pB[0][1][t];
        float kv = S.pB[1][0][t] + S.pB[1][1][t];
        float vv = S.pB[2][0][t] + S.pB[2][1][t];
        voutg[s * D + t] = vv;
        S.qrow[t] = qv;
        S.krow[t] = kv;
    }
    __syncthreads();
    if (t < 128) {
        int c = t & (HD - 1);
        int m = c >> 1;
        float fr = (float)s * expf(-(float)m * 1.15129254649702283e+00f);
        float cs = cosf(fr), sn = sinf(fr);
        int base = t & ~1;
        float qe = S.qrow[base], qod = S.qrow[base + 1];
        float ke = S.krow[base], kod = S.krow[base + 1];
        S.qs[t] = (c & 1) ? (qe * sn + qod * cs) : (qe * cs - qod * sn);
        koutg[s * D + t] = (c & 1) ? (ke * sn + kod * cs) : (ke * cs - kod * sn);
    }
}

template <int MODE>
__device__ __forceinline__ void layer_phase(
    int s, int t, SM& S, const float* __restrict__ kg, const float* __restrict__ vg,
    const float* __restrict__ wo, const float* __restrict__ n2w,
    const float* __restrict__ w1, const float* __restrict__ w3,
    const float* __restrict__ w2, const float* __restrict__ wq,
    const float* __restrict__ wk, const float* __restrict__ wv,
    const float* __restrict__ n1w, float* __restrict__ kout, float* __restrict__ vout,
    const float* __restrict__ fw, float* __restrict__ xng) {
    int col = t & 127, grp = t >> 7;
    // prefetch: K slices (2 heads), V quarter, wo quarter — issued up front
    float4 ka0, ka1, ka2, ka3, kb0, kb1, kb2, kb3;
    {
        const float4* p = (const float4*)&kg[col * D + grp * HD];
        ka0 = p[0]; ka1 = p[1]; ka2 = p[2]; ka3 = p[3];
        const float4* p2 = (const float4*)&kg[col * D + (grp + 4) * HD];
        kb0 = p2[0]; kb1 = p2[1]; kb2 = p2[2]; kb3 = p2[3];
    }
    float vpre[32], wopre[32];
    #pragma unroll
    for (int u = 0; u < 32; ++u) vpre[u] = vg[(grp * 32 + u) * D + col];
    #pragma unroll
    for (int u = 0; u < 32; ++u) wopre[u] = wo[(grp * 32 + u) * D + col];

    // scores (j=col; heads grp, grp+4); causal zero-fill
    {
        const float* qh = &S.qs[grp * HD];
        float a = ka0.x * qh[0] + ka0.y * qh[1] + ka0.z * qh[2] + ka0.w * qh[3] +
                  ka1.x * qh[4] + ka1.y * qh[5] + ka1.z * qh[6] + ka1.w * qh[7] +
                  ka2.x * qh[8] + ka2.y * qh[9] + ka2.z * qh[10] + ka2.w * qh[11] +
                  ka3.x * qh[12] + ka3.y * qh[13] + ka3.z * qh[14] + ka3.w * qh[15];
        const float* qh2 = &S.qs[(grp + 4) * HD];
        float b = kb0.x * qh2[0] + kb0.y * qh2[1] + kb0.z * qh2[2] + kb0.w * qh2[3] +
                  kb1.x * qh2[4] + kb1.y * qh2[5] + kb1.z * qh2[6] + kb1.w * qh2[7] +
                  kb2.x * qh2[8] + kb2.y * qh2[9] + kb2.z * qh2[10] + kb2.w * qh2[11] +
                  kb3.x * qh2[12] + kb3.y * qh2[13] + kb3.z * qh2[14] + kb3.w * qh2[15];
        S.ps[grp][col] = (col <= s) ? a * 0.25f : 0.f;
        S.ps[grp + 4][col] = (col <= s) ? b * 0.25f : 0.f;
    }
    __syncthreads();
    // softmax: one wave per head
    {
        int h = t >> 6, lane = t & 63;
        float v0 = (lane <= s) ? S.ps[h][lane] : -1e30f;
        float v1 = (lane + 64 <= s) ? S.ps[h][lane + 64] : -1e30f;
        float pm = fmaxf(v0, v1);
        #pragma unroll
        for (int m = 32; m > 0; m >>= 1) pm = fmaxf(pm, __shfl_xor(pm, m));
        float e0 = (lane <= s) ? __expf(v0 - pm) : 0.f;
        float e1 = (lane + 64 <= s) ? __expf(v1 - pm) : 0.f;
        S.ps[h][lane] = e0;
        S.ps[h][lane + 64] = e1;
        float sm = e0 + e1;
        #pragma unroll
        for (int m = 32; m > 0; m >>= 1) sm += __shfl_xor(sm, m);
        if (lane == 0) S.rl[h] = 1.0f / sm;
    }
    __syncthreads();
    // o partials from prefetched V
    {
        int h = col >> 4, jlo = grp * 32;
        float a0 = 0, a1 = 0, a2 = 0, a3 = 0;
        #pragma unroll
        for (int u = 0; u < 32; u += 4) {
            a0 += S.ps[h][jlo + u] * vpre[u];
            a1 += S.ps[h][jlo + u + 1] * vpre[u + 1];
            a2 += S.ps[h][jlo + u + 2] * vpre[u + 2];
            a3 += S.ps[h][jlo + u + 3] * vpre[u + 3];
        }
        S.parts4[grp][col] = (a0 + a1) + (a2 + a3);
    }
    __syncthreads();
    if (t < 128)
        S.orow[t] = (S.parts4[0][t] + S.parts4[1][t] + S.parts4[2][t] + S.parts4[3][t]) * S.rl[t >> 4];
    __syncthreads();
    // wo from prefetched registers
    {
        int dlo = grp * 32;
        float a0 = 0, a1 = 0;
        #pragma unroll
        for (int u = 0; u < 32; u += 2) {
            a0 += S.orow[dlo + u] * wopre[u];
            a1 += S.orow[dlo + u + 1] * wopre[u + 1];
        }
        S.parts4[grp][col] = a0 + a1;
    }
    __syncthreads();
    float xn = 0.f;
    if (t < 128)
        xn = S.xrow[t] + S.parts4[0][t] + S.parts4[1][t] + S.parts4[2][t] + S.parts4[3][t];
    float ss2 = block_sum512((t < 128) ? xn * xn : 0.f, S.scr);
    float r2 = 1.0f / sqrtf(ss2 * (1.0f / D) + EPS);
    if (t < 128) S.h2[t] = xn * r2 * n2w[t];
    __syncthreads();
    // FFN1: 682 col-dots over 512 threads (t<170 fused dual-dot)
    if (t < 170) {
        float a0 = 0, a1 = 0, b0 = 0, b1 = 0;
        #pragma unroll 8
        for (int d = 0; d < D; d += 2) {
            a0 += S.h2[d] * w1[d * HID + t];
            a1 += S.h2[d + 1] * w1[(d + 1) * HID + t];
            b0 += S.h2[d] * w3[d * HID + t + 171];
            b1 += S.h2[d + 1] * w3[(d + 1) * HID + t + 171];
        }
        S.afA[t] = a0 + a1;
        S.afB[t + 171] = b0 + b1;
    } else if (t < 341) {
        float a0 = 0, a1 = 0, a2 = 0, a3 = 0;
        #pragma unroll 8
        for (int d = 0; d < D; d += 4) {
            a0 += S.h2[d] * w1[d * HID + t];
            a1 += S.h2[d + 1] * w1[(d + 1) * HID + t];
            a2 += S.h2[d + 2] * w1[(d + 2) * HID + t];
            a3 += S.h2[d + 3] * w1[(d + 3) * HID + t];
        }
        S.afA[t] = (a0 + a1) + (a2 + a3);
    } else {
        int c2 = t - 341;
        float a0 = 0, a1 = 0, a2 = 0, a3 = 0;
        #pragma unroll 8
        for (int d = 0; d < D; d += 4) {
            a0 += S.h2[d] * w3[d * HID + c2];
            a1 += S.h2[d + 1] * w3[(d + 1) * HID + c2];
            a2 += S.h2[d + 2] * w3[(d + 2) * HID + c2];
            a3 += S.h2[d + 3] * w3[(d + 3) * HID + c2];
        }
        S.afB[c2] = (a0 + a1) + (a2 + a3);
    }
    __syncthreads();
    if (t < 341) {
        float a1v = S.afA[t];
        S.af[t] = (a1v / (1.0f + __expf(-a1v))) * S.afB[t];
    }
    __syncthreads();
    // FFN2: (col, quarter) split of the 341-sum
    {
        int lo = grp * 86;
        int hi = lo + 86;
        if (hi > HID) hi = HID;
        float a0 = 0, a1 = 0, a2 = 0, a3 = 0;
        int tt = lo;
        #pragma unroll 8
        for (; tt + 3 < hi; tt += 4) {
            a0 += S.af[tt] * w2[tt * D + col];
            a1 += S.af[tt + 1] * w2[(tt + 1) * D + col];
            a2 += S.af[tt + 2] * w2[(tt + 2) * D + col];
            a3 += S.af[tt + 3] * w2[(tt + 3) * D + col];
        }
        for (; tt < hi; ++tt) a0 += S.af[tt] * w2[tt * D + col];
        S.parts4[grp][col] = (a0 + a1) + (a2 + a3);
    }
    __syncthreads();
    float x2 = 0.f;
    if (t < 128) {
        x2 = xn + S.parts4[0][t] + S.parts4[1][t] + S.parts4[2][t] + S.parts4[3][t];
        S.xrow[t] = x2;
    }
    float ss3 = block_sum512((t < 128) ? x2 * x2 : 0.f, S.scr);
    float r3 = 1.0f / sqrtf(ss3 * (1.0f / D) + EPS);
    if constexpr (MODE == 0) {
        if (t < 128) S.h2[t] = x2 * r3 * n1w[t];
        __syncthreads();
        qkv_rope_512(s, t, S, wq, wk, wv, kout, vout);
    } else {
        float y = (t < 128) ? x2 * r3 * fw[t] : 0.f;
        float nn = block_sum512(y * y, S.scr);
        if (t < 128) xng[t * SEQ + s] = y / sqrtf(nn);
    }
}

__global__ __launch_bounds__(512, 2) void k_mega(
    const int* __restrict__ idx, const float* __restrict__ w_raw,
    const float* __restrict__ n1w, const float* __restrict__ n2w,
    const float* __restrict__ wq, const float* __restrict__ wk,
    const float* __restrict__ wv, const float* __restrict__ wo,
    const float* __restrict__ w1, const float* __restrict__ w3,
    const float* __restrict__ w2, const float* __restrict__ fnw,
    float* __restrict__ k1, float* __restrict__ v1, float* __restrict__ k2,
    float* __restrict__ v2, float* __restrict__ xng, unsigned* __restrict__ bar,
    float* __restrict__ sink) {
    __shared__ SM S;
    int t = threadIdx.x, s = blockIdx.x;
    unsigned gen0 = 0;
    if (t == 0) {
        atomicCAS(&bar[0], POISONU, 0u);
        atomicCAS(&bar[1], POISONU, 0u);
        gen0 = __hip_atomic_load(&bar[1], __ATOMIC_RELAXED, __HIP_MEMORY_SCOPE_AGENT);
    }
    // P1: embed gather (critical path) then warm-stream all weights into L3
    float xv = 0.f;
    if (t < 128) xv = sigm(w_raw[t * V + idx[s]]);
    float wacc = 0.f;
    int g = s * NTHR + t;  // 0..65535
    {
        const float4* p = (const float4*)w_raw;  // 262144 float4
        #pragma unroll
        for (int i = 0; i < 4; ++i) {
            float4 u = p[g + i * 65536];
            wacc += u.x + u.y + u.z + u.w;
        }
        if (g < 21824) {
            float4 u = ((const float4*)w1)[g]; wacc += u.x + u.y + u.z + u.w;
            float4 u2 = ((const float4*)w3)[g]; wacc += u2.x + u2.y + u2.z + u2.w;
            float4 u3 = ((const float4*)w2)[g]; wacc += u3.x + u3.y + u3.z + u3.w;
        }
        if (g < 8192) {
            float4 u = ((const float4*)wq)[g]; wacc += u.x + u.y + u.z + u.w;
            float4 u2 = ((const float4*)wk)[g]; wacc += u2.x + u2.y + u2.z + u2.w;
            float4 u3 = ((const float4*)wv)[g]; wacc += u3.x + u3.y + u3.z + u3.w;
            float4 u4 = ((const float4*)wo)[g]; wacc += u4.x + u4.y + u4.z + u4.w;
        }
    }
    if (t < 128) S.xrow[t] = xv;
    float ss = block_sum512((t < 128) ? xv * xv : 0.f, S.scr);
    float r = 1.0f / sqrtf(ss * (1.0f / D) + EPS);
    if (t < 128) S.h2[t] = xv * r * n1w[t];
    __syncthreads();
    qkv_rope_512(s, t, S, wq, wk, wv, k1, v1);
    if (wacc == 1234.5678f) sink[0] = wacc;  // defeat DCE, never taken
    grid_barrier(bar, gen0 + 1u);
    layer_phase<0>(s, t, S, k1, v1, wo, n2w, w1, w3, w2, wq + D * D, wk + D * D,
                   wv + D * D, n1w + D, k2, v2, (const float*)nullptr, (float*)nullptr);
    grid_barrier(bar, gen0 + 2u);
    layer_phase<1>(s, t, S, k2, v2, wo + D * D, n2w + D, w1 + D * HID, w3 + D * HID,
                   w2 + HID * D, (const float*)nullptr, (const float*)nullptr,
                   (const float*)nullptr, (const float*)nullptr, (float*)nullptr,
                   (float*)nullptr, fnw, xng);
}

// K2: logits[s,v] = clip(mean_d(xn[s,d] <= vn[v,d] ? 1 : vn[v,d]))  (unchanged)
__global__ __launch_bounds__(256) void k_logits(const float* __restrict__ xng,
                                                const float* __restrict__ w_raw,
                                                float* __restrict__ out) {
    __shared__ float xs[D * 64];
    __shared__ float vs[D * 32];
    __shared__ float nred[256];
    __shared__ float invn_s[32];
    int t = threadIdx.x;
    int sbase = (blockIdx.x & 1) * 64;
    int vbase = (blockIdx.x >> 1) * 32;
    for (int i = t; i < D * 64; i += 256) {
        int d = i >> 6, s2 = i & 63;
        xs[i] = xng[d * SEQ + sbase + s2];
    }
    for (int i = t; i < D * 32; i += 256) {
        int d = i >> 5, jj = i & 31;
        vs[i] = sigm(w_raw[d * V + vbase + jj]);
    }
    __syncthreads();
    {
        int colc = t & 31, dp = t >> 5;
        float p = 0.f;
        for (int u = 0; u < 16; ++u) {
            float vv = vs[(dp * 16 + u) * 32 + colc];
            p += vv * vv;
        }
        nred[t] = p;
    }
    __syncthreads();
    if (t < 32) {
        float sum = 0.f;
        for (int u = 0; u < 8; ++u) sum += nred[u * 32 + t];
        invn_s[t] = 1.0f / sqrtf(sum);
    }
    __syncthreads();
    for (int i = t; i < D * 32; i += 256) vs[i] *= invn_s[i & 31];
    __syncthreads();
    int vg = t & 15;
    int sg = t >> 4;
    float acc[4][2] = {};
    for (int d = 0; d < D; ++d) {
        float4 xq = *(const float4*)&xs[d * 64 + sg * 4];
        float2 vq = *(const float2*)&vs[d * 32 + vg * 2];
        acc[0][0] += (xq.x <= vq.x) ? 1.0f : vq.x;
        acc[0][1] += (xq.x <= vq.y) ? 1.0f : vq.y;
        acc[1][0] += (xq.y <= vq.x) ? 1.0f : vq.x;
        acc[1][1] += (xq.y <= vq.y) ? 1.0f : vq.y;
        acc[2][0] += (xq.z <= vq.x) ? 1.0f : vq.x;
        acc[2][1] += (xq.z <= vq.y) ? 1.0f : vq.y;
        acc[3][0] += (xq.w <= vq.x) ? 1.0f : vq.x;
        acc[3][1] += (xq.w <= vq.y) ? 1.0f : vq.y;
    }
    const float inv128 = 1.0f / 128.0f;
    #pragma unroll
    for (int si = 0; si < 4; ++si) {
        int s = sbase + sg * 4 + si;
        float2 ov;
        ov.x = fminf(fmaxf(acc[si][0] * inv128, 1e-6f), 1.0f - 1e-6f);
        ov.y = fminf(fmaxf(acc[si][1] * inv128, 1e-6f), 1.0f - 1e-6f);
        *(float2*)&out[s * V + vbase + vg * 2] = ov;
    }
}

extern "C" void kernel_launch(void* const* d_in, const int* in_sizes, int n_in,
                              void* d_out, int out_size, void* d_ws, size_t ws_size,
                              hipStream_t stream) {
    const int* idx = (const int*)d_in[0];
    const float* w_raw = (const float*)d_in[1];
    const float* n1w = (const float*)d_in[2];
    const float* n2w = (const float*)d_in[3];
    const float* wq = (const float*)d_in[4];
    const float* wk = (const float*)d_in[5];
    const float* wv = (const float*)d_in[6];
    const float* wo = (const float*)d_in[7];
    const float* w1 = (const float*)d_in[8];
    const float* w3 = (const float*)d_in[9];
    const float* w2 = (const float*)d_in[10];
    const float* fnw = (const float*)d_in[11];
    float* out = (float*)d_out;
    float* ws = (float*)d_ws;

    float* k1 = ws;                 // 16384
    float* v1 = ws + 16384;
    float* k2 = ws + 32768;
    float* v2 = ws + 49152;
    float* xng = ws + 65536;        // 16384
    unsigned* bar = (unsigned*)(ws + 81920);
    float* sink = ws + 81928;

    k_mega<<<dim3(NBLK), dim3(NTHR), 0, stream>>>(idx, w_raw, n1w, n2w, wq, wk, wv,
                                                  wo, w1, w3, w2, fnw, k1, v1, k2,
                                                  v2, xng, bar, sink);
    k_logits<<<dim3(512), dim3(256), 0, stream>>>(xng, w_raw, out);
}

// Round 6
// 196.950 us; speedup vs baseline: 1.1766x; 1.1766x over previous
//
#include <hip/hip_runtime.h>
#include <math.h>

#define V 8192
#define D 128
#define NH 8
#define HD 16
#define SEQ 128
#define HID 341
#define EPS 1e-6f

__device__ __forceinline__ float sigm(float x) { return 1.0f / (1.0f + __expf(-x)); }

// 256-thread block-wide sum. scratch >= 4 floats. 2 barriers.
__device__ __forceinline__ float block_sum256(float v, float* scratch) {
    #pragma unroll
    for (int m = 32; m > 0; m >>= 1) v += __shfl_xor(v, m);
    if ((threadIdx.x & 63) == 0) scratch[threadIdx.x >> 6] = v;
    __syncthreads();
    float s = (scratch[0] + scratch[1]) + (scratch[2] + scratch[3]);
    __syncthreads();
    return s;
}

// Two-row sum over a 512-thread block. Input must be nonzero only for t<256,
// with rows mapped t<128 -> row0, 128<=t<256 -> row1 (waves 0,1 / 2,3).
__device__ __forceinline__ float2 block_sum2(float v, float* scr) {
    #pragma unroll
    for (int m = 32; m > 0; m >>= 1) v += __shfl_xor(v, m);
    if ((threadIdx.x & 63) == 0) scr[threadIdx.x >> 6] = v;
    __syncthreads();
    float2 r;
    r.x = scr[0] + scr[1];
    r.y = scr[2] + scr[3];
    __syncthreads();
    return r;
}

// K1: embed + rms + qkv + rope. grid = SEQ + 256 (warm blocks), block=256
__global__ __launch_bounds__(256, 1) void k_embed_qkv(
    const int* __restrict__ idx, const float* __restrict__ w_raw,
    const float* __restrict__ wq, const float* __restrict__ wk,
    const float* __restrict__ wv, const float* __restrict__ n1w,
    const float* __restrict__ w1, const float* __restrict__ w3,
    const float* __restrict__ w2, const float* __restrict__ wo,
    float* __restrict__ x, float* __restrict__ q, float* __restrict__ k,
    float* __restrict__ v, float* __restrict__ sink) {
    int t = threadIdx.x;
    if (blockIdx.x >= SEQ) {
        // L3-warm: stream every weight once
        int g = (blockIdx.x - SEQ) * 256 + t;  // 0..65535
        float acc = 0.f;
        const float4* p = (const float4*)w_raw;  // 262144 float4
        for (int i = g; i < 262144; i += 65536) {
            float4 u = p[i];
            acc += u.x + u.y + u.z + u.w;
        }
        p = (const float4*)w1;
        if (g < 21824) { float4 u = p[g]; acc += u.x + u.y + u.z + u.w; }
        p = (const float4*)w3;
        if (g < 21824) { float4 u = p[g]; acc += u.x + u.y + u.z + u.w; }
        p = (const float4*)w2;
        if (g < 21824) { float4 u = p[g]; acc += u.x + u.y + u.z + u.w; }
        p = (const float4*)wq;
        if (g < 8192) { float4 u = p[g]; acc += u.x + u.y + u.z + u.w; }
        p = (const float4*)wk;
        if (g < 8192) { float4 u = p[g]; acc += u.x + u.y + u.z + u.w; }
        p = (const float4*)wv;
        if (g < 8192) { float4 u = p[g]; acc += u.x + u.y + u.z + u.w; }
        p = (const float4*)wo;
        if (g < 8192) { float4 u = p[g]; acc += u.x + u.y + u.z + u.w; }
        if (acc == 1234.5678f) sink[0] = acc;  // never true; defeats DCE
        return;
    }
    __shared__ float hr[D], qrow[D], krow[D], vpart[2][D], scr[4];
    int s = blockIdx.x;
    int col = t & 127, half = t >> 7, dlo = half * 64;
    float xv = 0.f;
    if (t < 128) xv = sigm(w_raw[t * V + idx[s]]);
    if (t < 128) x[s * D + t] = xv;
    float ss = block_sum256(xv * xv, scr);
    float r = 1.0f / sqrtf(ss * (1.0f / D) + EPS);
    if (t < 128) hr[t] = xv * r * n1w[t];
    __syncthreads();
    const float* wsel = (t < 128) ? wq : wk;
    float a0 = 0, a1 = 0, a2 = 0, a3 = 0;
    #pragma unroll 8
    for (int d = 0; d < 128; d += 4) {
        a0 += hr[d] * wsel[d * D + col];
        a1 += hr[d + 1] * wsel[(d + 1) * D + col];
        a2 += hr[d + 2] * wsel[(d + 2) * D + col];
        a3 += hr[d + 3] * wsel[(d + 3) * D + col];
    }
    float qk = (a0 + a1) + (a2 + a3);
    float b0 = 0, b1 = 0, b2 = 0, b3 = 0;
    #pragma unroll 8
    for (int d = dlo; d < dlo + 64; d += 4) {
        b0 += hr[d] * wv[d * D + col];
        b1 += hr[d + 1] * wv[(d + 1) * D + col];
        b2 += hr[d + 2] * wv[(d + 2) * D + col];
        b3 += hr[d + 3] * wv[(d + 3) * D + col];
    }
    vpart[half][col] = (b0 + b1) + (b2 + b3);
    if (t < 128) qrow[col] = qk;
    else krow[col] = qk;
    __syncthreads();
    if (t < 128) {
        v[s * D + t] = vpart[0][t] + vpart[1][t];
        int c = t & (HD - 1);
        int m = c >> 1;
        float fr = (float)s * expf(-(float)m * 1.15129254649702283e+00f);
        float cs = cosf(fr), sn = sinf(fr);
        int base = t & ~1;
        float qe = qrow[base], qod = qrow[base + 1];
        float ke = krow[base], kod = krow[base + 1];
        q[s * D + t] = (c & 1) ? (qe * sn + qod * cs) : (qe * cs - qod * sn);
        k[s * D + t] = (c & 1) ? (ke * sn + kod * cs) : (ke * cs - kod * sn);
    }
}

// K2/K3: fused layer, 2 rows per block. grid=SEQ/2, block=512.
template <int MODE>
__global__ __launch_bounds__(512, 1) void k_layer2(
    const float* __restrict__ q, const float* __restrict__ kg,
    const float* __restrict__ vg, float* __restrict__ x,
    const float* __restrict__ wo, const float* __restrict__ n2w,
    const float* __restrict__ w1, const float* __restrict__ w3,
    const float* __restrict__ w2, const float* __restrict__ wq,
    const float* __restrict__ wk, const float* __restrict__ wv,
    const float* __restrict__ n1w, float* __restrict__ qo, float* __restrict__ ko,
    float* __restrict__ vo, const float* __restrict__ fw, float* __restrict__ xng) {
    __shared__ float ps[2][NH][SEQ + 2];
    __shared__ float op[4][2][D];
    __shared__ float qs[2][D], orow[2][D], h2[2][D];
    __shared__ float afA[2][HID], afB[2][HID], af[2][HID];
    __shared__ float qkvo[3][2][D];
    __shared__ float rl[2][NH];
    __shared__ float scr[8];
    int t = threadIdx.x;
    int s0 = blockIdx.x * 2;
    int col = t & 127, grp = t >> 7;  // grp in 0..3; for t<256 grp = row

    // load q rows (t>=256) and residual rows (t<256, register)
    float xr = 0.f;
    if (t < 256) xr = x[(s0 + grp) * D + col];
    else qs[grp - 2][col] = q[(s0 + grp - 2) * D + col];
    __syncthreads();

    // scores: thread (j=col, head-pair grp/grp+4), both rows. K read once/block.
    {
        int j = col;
        const float4* p = (const float4*)&kg[j * D + grp * HD];
        float4 ka0 = p[0], ka1 = p[1], ka2 = p[2], ka3 = p[3];
        const float4* p2 = (const float4*)&kg[j * D + (grp + 4) * HD];
        float4 kb0 = p2[0], kb1 = p2[1], kb2 = p2[2], kb3 = p2[3];
        #pragma unroll
        for (int r = 0; r < 2; ++r) {
            const float* qa = &qs[r][grp * HD];
            float a = ka0.x * qa[0] + ka0.y * qa[1] + ka0.z * qa[2] + ka0.w * qa[3] +
                      ka1.x * qa[4] + ka1.y * qa[5] + ka1.z * qa[6] + ka1.w * qa[7] +
                      ka2.x * qa[8] + ka2.y * qa[9] + ka2.z * qa[10] + ka2.w * qa[11] +
                      ka3.x * qa[12] + ka3.y * qa[13] + ka3.z * qa[14] + ka3.w * qa[15];
            const float* qb = &qs[r][(grp + 4) * HD];
            float b = kb0.x * qb[0] + kb0.y * qb[1] + kb0.z * qb[2] + kb0.w * qb[3] +
                      kb1.x * qb[4] + kb1.y * qb[5] + kb1.z * qb[6] + kb1.w * qb[7] +
                      kb2.x * qb[8] + kb2.y * qb[9] + kb2.z * qb[10] + kb2.w * qb[11] +
                      kb3.x * qb[12] + kb3.y * qb[13] + kb3.z * qb[14] + kb3.w * qb[15];
            int sr = s0 + r;
            ps[r][grp][j] = (j <= sr) ? a * 0.25f : 0.f;
            ps[r][grp + 4][j] = (j <= sr) ? b * 0.25f : 0.f;
        }
    }
    __syncthreads();

    // softmax: 16 (row,head) tasks; wave w handles tasks 2w+(lane>>5), 32 lanes each
    {
        int lane = t & 63;
        int idx = (t >> 6) * 2 + (lane >> 5);
        int r = idx >> 3, h = idx & 7;
        int sr = s0 + r;
        int l32 = lane & 31;
        float pm = -1e30f;
        for (int j = l32; j <= sr; j += 32) pm = fmaxf(pm, ps[r][h][j]);
        #pragma unroll
        for (int m = 16; m > 0; m >>= 1) pm = fmaxf(pm, __shfl_xor(pm, m, 32));
        float sum = 0.f;
        for (int j = l32; j <= sr; j += 32) {
            float e = __expf(ps[r][h][j] - pm);
            ps[r][h][j] = e;
            sum += e;
        }
        #pragma unroll
        for (int m = 16; m > 0; m >>= 1) sum += __shfl_xor(sum, m, 32);
        if (l32 == 0) rl[r][h] = 1.0f / sum;
    }
    __syncthreads();

    // o: thread (c=col, j-quarter grp); V loaded once, used for both rows
    {
        int h = col >> 4, jlo = grp * 32;
        float vpre[32];
        #pragma unroll
        for (int u = 0; u < 32; ++u) vpre[u] = vg[(jlo + u) * D + col];
        float a00 = 0, a01 = 0, a10 = 0, a11 = 0;
        #pragma unroll
        for (int u = 0; u < 32; u += 2) {
            a00 += ps[0][h][jlo + u] * vpre[u];
            a01 += ps[0][h][jlo + u + 1] * vpre[u + 1];
            a10 += ps[1][h][jlo + u] * vpre[u];
            a11 += ps[1][h][jlo + u + 1] * vpre[u + 1];
        }
        op[grp][0][col] = a00 + a01;
        op[grp][1][col] = a10 + a11;
    }
    __syncthreads();
    if (t < 256)
        orow[grp][col] =
            (op[0][grp][col] + op[1][grp][col] + op[2][grp][col] + op[3][grp][col]) *
            rl[grp][col >> 4];
    __syncthreads();

    // wo: thread (c, d-quarter grp), both rows per weight
    {
        int dlo = grp * 32;
        float wp[32];
        #pragma unroll
        for (int u = 0; u < 32; ++u) wp[u] = wo[(dlo + u) * D + col];
        float a00 = 0, a01 = 0, a10 = 0, a11 = 0;
        #pragma unroll
        for (int u = 0; u < 32; u += 2) {
            a00 += orow[0][dlo + u] * wp[u];
            a01 += orow[0][dlo + u + 1] * wp[u + 1];
            a10 += orow[1][dlo + u] * wp[u];
            a11 += orow[1][dlo + u + 1] * wp[u + 1];
        }
        op[grp][0][col] = a00 + a01;
        op[grp][1][col] = a10 + a11;
    }
    __syncthreads();
    float xn = 0.f;
    if (t < 256)
        xn = xr + op[0][grp][col] + op[1][grp][col] + op[2][grp][col] + op[3][grp][col];
    float2 ss2 = block_sum2((t < 256) ? xn * xn : 0.f, scr);
    if (t < 256) {
        float rr = 1.0f / sqrtf(((grp == 0) ? ss2.x : ss2.y) * (1.0f / D) + EPS);
        h2[grp][col] = xn * rr * n2w[col];
    }
    __syncthreads();

    // FFN1: 682 col-tasks, each weight used for both rows (4 FMA chains)
    for (int task = t; task < 2 * HID; task += 512) {
        int mat = task >= HID;
        int c2 = task - (mat ? HID : 0);
        const float* w = mat ? w3 : w1;
        float a00 = 0, a01 = 0, a10 = 0, a11 = 0;
        #pragma unroll 8
        for (int d = 0; d < D; d += 2) {
            float w0 = w[d * HID + c2], w1v = w[(d + 1) * HID + c2];
            a00 += h2[0][d] * w0;
            a01 += h2[0][d + 1] * w1v;
            a10 += h2[1][d] * w0;
            a11 += h2[1][d + 1] * w1v;
        }
        if (mat) {
            afB[0][c2] = a00 + a01;
            afB[1][c2] = a10 + a11;
        } else {
            afA[0][c2] = a00 + a01;
            afA[1][c2] = a10 + a11;
        }
    }
    __syncthreads();
    for (int task = t; task < 2 * HID; task += 512) {
        int r = task >= HID;
        int c2 = task - (r ? HID : 0);
        float a = afA[r][c2];
        af[r][c2] = (a / (1.0f + __expf(-a))) * afB[r][c2];
    }
    __syncthreads();

    // FFN2: thread (c, k-quarter grp), both rows per weight
    {
        int lo = grp * 86, hi = lo + 86;
        if (hi > HID) hi = HID;
        float a00 = 0, a01 = 0, a10 = 0, a11 = 0;
        int tt = lo;
        #pragma unroll 8
        for (; tt + 1 < hi; tt += 2) {
            float w0 = w2[tt * D + col], w1v = w2[(tt + 1) * D + col];
            a00 += af[0][tt] * w0;
            a01 += af[0][tt + 1] * w1v;
            a10 += af[1][tt] * w0;
            a11 += af[1][tt + 1] * w1v;
        }
        for (; tt < hi; ++tt) {
            float w0 = w2[tt * D + col];
            a00 += af[0][tt] * w0;
            a10 += af[1][tt] * w0;
        }
        op[grp][0][col] = a00 + a01;
        op[grp][1][col] = a10 + a11;
    }
    __syncthreads();
    float x2 = 0.f;
    if (t < 256) {
        x2 = xn + op[0][grp][col] + op[1][grp][col] + op[2][grp][col] + op[3][grp][col];
        if (MODE == 0) x[(s0 + grp) * D + col] = x2;
    }
    float2 ss3 = block_sum2((t < 256) ? x2 * x2 : 0.f, scr);

    if constexpr (MODE == 0) {
        if (t < 256) {
            float rr = 1.0f / sqrtf(((grp == 0) ? ss3.x : ss3.y) * (1.0f / D) + EPS);
            h2[grp][col] = x2 * rr * n1w[col];
        }
        __syncthreads();
        // next-layer QKV: 384 col-tasks (q/k/v), both rows per weight
        if (t < 384) {
            int which = grp;  // 0=q, 1=k, 2=v
            const float* w = (which == 0) ? wq : (which == 1) ? wk : wv;
            float a00 = 0, a01 = 0, a10 = 0, a11 = 0;
            #pragma unroll 8
            for (int d = 0; d < D; d += 2) {
                float w0 = w[d * D + col], w1v = w[(d + 1) * D + col];
                a00 += h2[0][d] * w0;
                a01 += h2[0][d + 1] * w1v;
                a10 += h2[1][d] * w0;
                a11 += h2[1][d + 1] * w1v;
            }
            qkvo[which][0][col] = a00 + a01;
            qkvo[which][1][col] = a10 + a11;
        }
        __syncthreads();
        if (t < 256) {
            int r = grp, s = s0 + r;
            vo[s * D + col] = qkvo[2][r][col];
            int c = col & (HD - 1);
            int m = c >> 1;
            float fr = (float)s * expf(-(float)m * 1.15129254649702283e+00f);
            float cs = cosf(fr), sn = sinf(fr);
            int base = col & ~1;
            float qe = qkvo[0][r][base], qod = qkvo[0][r][base + 1];
            float ke = qkvo[1][r][base], kod = qkvo[1][r][base + 1];
            qo[s * D + col] = (c & 1) ? (qe * sn + qod * cs) : (qe * cs - qod * sn);
            ko[s * D + col] = (c & 1) ? (ke * sn + kod * cs) : (ke * cs - kod * sn);
        }
    } else {
        float y = 0.f;
        if (t < 256) {
            float rr = 1.0f / sqrtf(((grp == 0) ? ss3.x : ss3.y) * (1.0f / D) + EPS);
            y = x2 * rr * fw[col];
        }
        float2 nn = block_sum2(y * y, scr);
        if (t < 256) xng[col * SEQ + s0 + grp] = y / sqrtf((grp == 0) ? nn.x : nn.y);
    }
}

// K4: logits[s,v] = clip(mean_d(xn[s,d] <= vn[v,d] ? 1 : vn[v,d]))
__global__ __launch_bounds__(256) void k_logits(const float* __restrict__ xng,
                                                const float* __restrict__ w_raw,
                                                float* __restrict__ out) {
    __shared__ float xs[D * 64];
    __shared__ float vs[D * 32];
    __shared__ float nred[256];
    __shared__ float invn_s[32];
    int t = threadIdx.x;
    int sbase = (blockIdx.x & 1) * 64;
    int vbase = (blockIdx.x >> 1) * 32;
    for (int i = t; i < D * 64; i += 256) {
        int d = i >> 6, s2 = i & 63;
        xs[i] = xng[d * SEQ + sbase + s2];
    }
    for (int i = t; i < D * 32; i += 256) {
        int d = i >> 5, jj = i & 31;
        vs[i] = sigm(w_raw[d * V + vbase + jj]);
    }
    __syncthreads();
    {
        int colc = t & 31, dp = t >> 5;
        float p = 0.f;
        for (int u = 0; u < 16; ++u) {
            float vv = vs[(dp * 16 + u) * 32 + colc];
            p += vv * vv;
        }
        nred[t] = p;
    }
    __syncthreads();
    if (t < 32) {
        float sum = 0.f;
        for (int u = 0; u < 8; ++u) sum += nred[u * 32 + t];
        invn_s[t] = 1.0f / sqrtf(sum);
    }
    __syncthreads();
    for (int i = t; i < D * 32; i += 256) vs[i] *= invn_s[i & 31];
    __syncthreads();
    int vg = t & 15;
    int sg = t >> 4;
    float acc[4][2] = {};
    for (int d = 0; d < D; ++d) {
        float4 xq = *(const float4*)&xs[d * 64 + sg * 4];
        float2 vq = *(const float2*)&vs[d * 32 + vg * 2];
        acc[0][0] += (xq.x <= vq.x) ? 1.0f : vq.x;
        acc[0][1] += (xq.x <= vq.y) ? 1.0f : vq.y;
        acc[1][0] += (xq.y <= vq.x) ? 1.0f : vq.x;
        acc[1][1] += (xq.y <= vq.y) ? 1.0f : vq.y;
        acc[2][0] += (xq.z <= vq.x) ? 1.0f : vq.x;
        acc[2][1] += (xq.z <= vq.y) ? 1.0f : vq.y;
        acc[3][0] += (xq.w <= vq.x) ? 1.0f : vq.x;
        acc[3][1] += (xq.w <= vq.y) ? 1.0f : vq.y;
    }
    const float inv128 = 1.0f / 128.0f;
    #pragma unroll
    for (int si = 0; si < 4; ++si) {
        int s = sbase + sg * 4 + si;
        float2 ov;
        ov.x = fminf(fmaxf(acc[si][0] * inv128, 1e-6f), 1.0f - 1e-6f);
        ov.y = fminf(fmaxf(acc[si][1] * inv128, 1e-6f), 1.0f - 1e-6f);
        *(float2*)&out[s * V + vbase + vg * 2] = ov;
    }
}

extern "C" void kernel_launch(void* const* d_in, const int* in_sizes, int n_in,
                              void* d_out, int out_size, void* d_ws, size_t ws_size,
                              hipStream_t stream) {
    const int* idx = (const int*)d_in[0];
    const float* w_raw = (const float*)d_in[1];
    const float* n1w = (const float*)d_in[2];
    const float* n2w = (const float*)d_in[3];
    const float* wq = (const float*)d_in[4];
    const float* wk = (const float*)d_in[5];
    const float* wv = (const float*)d_in[6];
    const float* wo = (const float*)d_in[7];
    const float* w1 = (const float*)d_in[8];
    const float* w3 = (const float*)d_in[9];
    const float* w2 = (const float*)d_in[10];
    const float* fnw = (const float*)d_in[11];
    float* out = (float*)d_out;
    float* ws = (float*)d_ws;

    float* x    = ws;
    float* q1   = ws + 16384;
    float* k1   = ws + 32768;
    float* v1   = ws + 49152;
    float* q2   = ws + 65536;
    float* k2   = ws + 81920;
    float* v2   = ws + 98304;
    float* xng  = ws + 114688;
    float* sink = ws + 131072;

    k_embed_qkv<<<dim3(SEQ + 256), dim3(256), 0, stream>>>(
        idx, w_raw, wq, wk, wv, n1w, w1, w3, w2, wo, x, q1, k1, v1, sink);
    k_layer2<0><<<dim3(SEQ / 2), dim3(512), 0, stream>>>(
        q1, k1, v1, x, wo, n2w, w1, w3, w2,
        wq + D * D, wk + D * D, wv + D * D, n1w + D, q2, k2, v2,
        (const float*)nullptr, (float*)nullptr);
    k_layer2<1><<<dim3(SEQ / 2), dim3(512), 0, stream>>>(
        q2, k2, v2, x, wo + D * D, n2w + D, w1 + D * HID, w3 + D * HID,
        w2 + HID * D, (const float*)nullptr, (const float*)nullptr,
        (const float*)nullptr, (const float*)nullptr, (float*)nullptr,
        (float*)nullptr, (float*)nullptr, fnw, xng);
    k_logits<<<dim3(512), dim3(256), 0, stream>>>(xng, w_raw, out);
}

// Round 7
// 165.341 us; speedup vs baseline: 1.4015x; 1.1912x over previous
//
#include <hip/hip_runtime.h>
#include <math.h>

#define V 8192
#define D 128
#define NH 8
#define HD 16
#define SEQ 128
#define HID 341
#define HIDP 344
#define EPS 1e-6f

__device__ __forceinline__ float sigm(float x) { return 1.0f / (1.0f + __expf(-x)); }

// 256-thread block-wide sum. scratch >= 4 floats. 2 barriers.
__device__ __forceinline__ float block_sum256(float v, float* scratch) {
    #pragma unroll
    for (int m = 32; m > 0; m >>= 1) v += __shfl_xor(v, m);
    if ((threadIdx.x & 63) == 0) scratch[threadIdx.x >> 6] = v;
    __syncthreads();
    float s = (scratch[0] + scratch[1]) + (scratch[2] + scratch[3]);
    __syncthreads();
    return s;
}

// K1: row blocks: embed + rms + qkv + rope (original layouts).
// Warm blocks (blockIdx >= SEQ): repack all weights transposed into ws + stream w_raw.
__global__ __launch_bounds__(256, 1) void k_embed_qkv(
    const int* __restrict__ idx, const float* __restrict__ w_raw,
    const float* __restrict__ wq, const float* __restrict__ wk,
    const float* __restrict__ wv, const float* __restrict__ wo,
    const float* __restrict__ w1, const float* __restrict__ w3,
    const float* __restrict__ w2, const float* __restrict__ n1w,
    float* __restrict__ x, float* __restrict__ q, float* __restrict__ k,
    float* __restrict__ vt, float* __restrict__ wqT, float* __restrict__ wkT,
    float* __restrict__ wvT, float* __restrict__ woT, float* __restrict__ w1T,
    float* __restrict__ w3T, float* __restrict__ w2T, float* __restrict__ sink) {
    int t = threadIdx.x;
    if (blockIdx.x >= SEQ) {
        int g = (blockIdx.x - SEQ) * 256 + t;  // 0..65535
        // transpose 128x128 mats (read coalesced, write strided)
        if (g < 32768) {
            int l = g >> 14, rem = g & 16383, d = rem >> 7, c = rem & 127;
            int o = l * 16384 + c * 128 + d;
            wqT[o] = wq[g];
            wkT[o] = wk[g];
            wvT[o] = wv[g];
            woT[o] = wo[g];
        }
        // w1T/w3T [l][c][d] = w[l][d*341+c]  (write coalesced)
        for (int i = g; i < 2 * 43648; i += 65536) {
            int l = i >= 43648;
            int r = i - (l ? 43648 : 0);
            int c = r >> 7, d = r & 127;
            w1T[i] = w1[l * 43648 + d * HID + c];
            w3T[i] = w3[l * 43648 + d * HID + c];
        }
        // w2T [l][c][344] = w2[l][k*128+c], zero-pad k>=341 (write coalesced)
        for (int i = g; i < 2 * 44032; i += 65536) {
            int l = i >= 44032;
            int r = i - (l ? 44032 : 0);
            int c = r / HIDP;
            int kk = r - c * HIDP;
            w2T[i] = (kk < HID) ? w2[l * 43648 + kk * 128 + c] : 0.f;
        }
        // stream w_raw to warm L3
        float acc = 0.f;
        const float4* p = (const float4*)w_raw;
        #pragma unroll
        for (int i = 0; i < 4; ++i) {
            float4 u = p[g + i * 65536];
            acc += u.x + u.y + u.z + u.w;
        }
        if (acc == 1234.5678f) sink[0] = acc;
        return;
    }
    __shared__ float hr[D], qrow[D], krow[D], vpart[2][D], scr[4];
    int s = blockIdx.x;
    int col = t & 127, half = t >> 7, dlo = half * 64;
    float xv = 0.f;
    if (t < 128) xv = sigm(w_raw[t * V + idx[s]]);
    if (t < 128) x[s * D + t] = xv;
    float ss = block_sum256(xv * xv, scr);
    float r = 1.0f / sqrtf(ss * (1.0f / D) + EPS);
    if (t < 128) hr[t] = xv * r * n1w[t];
    __syncthreads();
    const float* wsel = (t < 128) ? wq : wk;
    float a0 = 0, a1 = 0, a2 = 0, a3 = 0;
    #pragma unroll 8
    for (int d = 0; d < 128; d += 4) {
        a0 += hr[d] * wsel[d * D + col];
        a1 += hr[d + 1] * wsel[(d + 1) * D + col];
        a2 += hr[d + 2] * wsel[(d + 2) * D + col];
        a3 += hr[d + 3] * wsel[(d + 3) * D + col];
    }
    float qk = (a0 + a1) + (a2 + a3);
    float b0 = 0, b1 = 0, b2 = 0, b3 = 0;
    #pragma unroll 8
    for (int d = dlo; d < dlo + 64; d += 4) {
        b0 += hr[d] * wv[d * D + col];
        b1 += hr[d + 1] * wv[(d + 1) * D + col];
        b2 += hr[d + 2] * wv[(d + 2) * D + col];
        b3 += hr[d + 3] * wv[(d + 3) * D + col];
    }
    vpart[half][col] = (b0 + b1) + (b2 + b3);
    if (t < 128) qrow[col] = qk;
    else krow[col] = qk;
    __syncthreads();
    if (t < 128) {
        vt[t * SEQ + s] = vpart[0][t] + vpart[1][t];  // V transposed
        int c = t & (HD - 1);
        int m = c >> 1;
        float fr = (float)s * expf(-(float)m * 1.15129254649702283e+00f);
        float cs = cosf(fr), sn = sinf(fr);
        int base = t & ~1;
        float qe = qrow[base], qod = qrow[base + 1];
        float ke = krow[base], kod = krow[base + 1];
        q[s * D + t] = (c & 1) ? (qe * sn + qod * cs) : (qe * cs - qod * sn);
        k[s * D + t] = (c & 1) ? (ke * sn + kod * cs) : (ke * cs - kod * sn);
    }
}

// K2/K3: fused layer per row with transposed weights (all float4 chains).
// grid=SEQ, block=256
template <int MODE>
__global__ __launch_bounds__(256, 1) void k_layer(
    const float* __restrict__ q, const float* __restrict__ kg,
    const float* __restrict__ vt, float* __restrict__ x,
    const float* __restrict__ woT, const float* __restrict__ n2w,
    const float* __restrict__ w1T, const float* __restrict__ w3T,
    const float* __restrict__ w2T, const float* __restrict__ wqT,
    const float* __restrict__ wkT, const float* __restrict__ wvT,
    const float* __restrict__ n1w, float* __restrict__ qo, float* __restrict__ ko,
    float* __restrict__ vto, const float* __restrict__ fw, float* __restrict__ xng) {
    __shared__ float ps[NH][SEQ + 2];
    __shared__ float qs[D], orow[D], qrow[D], krow[D];
    __shared__ float part[2][D];
    __shared__ float4 h24[32];   // h2[128]
    __shared__ float4 af4[86];   // af[344], tail zeroed
    __shared__ float afA[HID], afB[HID];
    __shared__ float rl[NH];
    __shared__ float scr[4];
    float* h2 = (float*)h24;
    float* af = (float*)af4;
    int s = blockIdx.x, t = threadIdx.x;
    int col = t & 127, half = t >> 7;

    float xr = 0.f;
    if (t < 128) {
        qs[t] = q[s * D + t];
        xr = x[s * D + t];
    }
    __syncthreads();

    // scores: thread (j=col, heads half+2u); 16 float4 loads
    {
        int j = col;
        #pragma unroll
        for (int u = 0; u < 4; ++u) {
            int h = half + 2 * u;
            const float4* kp = (const float4*)&kg[j * D + h * HD];
            float4 k0 = kp[0], k1 = kp[1], k2 = kp[2], k3 = kp[3];
            const float* qh = &qs[h * HD];
            float acc = k0.x * qh[0] + k0.y * qh[1] + k0.z * qh[2] + k0.w * qh[3] +
                        k1.x * qh[4] + k1.y * qh[5] + k1.z * qh[6] + k1.w * qh[7] +
                        k2.x * qh[8] + k2.y * qh[9] + k2.z * qh[10] + k2.w * qh[11] +
                        k3.x * qh[12] + k3.y * qh[13] + k3.z * qh[14] + k3.w * qh[15];
            ps[h][j] = (j <= s) ? acc * 0.25f : 0.f;
        }
    }
    __syncthreads();

    // softmax over j<=s: head = t>>5, 32 lanes
    {
        int h = t >> 5, lane = t & 31;
        float pm = -1e30f;
        for (int j = lane; j <= s; j += 32) pm = fmaxf(pm, ps[h][j]);
        #pragma unroll
        for (int m = 16; m > 0; m >>= 1) pm = fmaxf(pm, __shfl_xor(pm, m, 32));
        float psum = 0.f;
        for (int j = lane; j <= s; j += 32) {
            float e = __expf(ps[h][j] - pm);
            ps[h][j] = e;
            psum += e;
        }
        #pragma unroll
        for (int m = 16; m > 0; m >>= 1) psum += __shfl_xor(psum, m, 32);
        if (lane == 0) rl[h] = 1.0f / psum;
    }
    __syncthreads();

    // o: V^T contiguous; thread (c=col, j-half); 16 float4
    {
        int h = col >> 4, jlo = half * 64;
        const float4* vp = (const float4*)&vt[col * SEQ + jlo];
        float a0 = 0, a1 = 0, a2 = 0, a3 = 0;
        #pragma unroll
        for (int i = 0; i < 16; ++i) {
            float4 vv = vp[i];
            int j = jlo + 4 * i;
            a0 += ps[h][j] * vv.x;
            a1 += ps[h][j + 1] * vv.y;
            a2 += ps[h][j + 2] * vv.z;
            a3 += ps[h][j + 3] * vv.w;
        }
        part[half][col] = (a0 + a1) + (a2 + a3);
    }
    __syncthreads();
    if (t < 128) orow[t] = (part[0][t] + part[1][t]) * rl[t >> 4];
    __syncthreads();

    // wo: woT contiguous; thread (c, d-half); 16 float4
    {
        int dlo = half * 64;
        const float4* wp = (const float4*)&woT[col * 128 + dlo];
        float a0 = 0, a1 = 0, a2 = 0, a3 = 0;
        #pragma unroll
        for (int i = 0; i < 16; ++i) {
            float4 ww = wp[i];
            int d = dlo + 4 * i;
            a0 += orow[d] * ww.x;
            a1 += orow[d + 1] * ww.y;
            a2 += orow[d + 2] * ww.z;
            a3 += orow[d + 3] * ww.w;
        }
        part[half][col] = (a0 + a1) + (a2 + a3);
    }
    __syncthreads();
    float xn = 0.f;
    if (t < 128) xn = xr + part[0][t] + part[1][t];
    float ss2 = block_sum256((t < 128) ? xn * xn : 0.f, scr);
    float r2 = 1.0f / sqrtf(ss2 * (1.0f / D) + EPS);
    if (t < 128) h2[t] = xn * r2 * n2w[t];
    __syncthreads();

    // FFN1: 682 col-dots; 3 independent float4 streams per thread
    {
        int u1 = t, u2 = t + 256, u3 = t + 512;
        const float4* pa = (const float4*)&w1T[u1 * 128];  // u1<256<341 always w1T
        const float4* pb = (const float4*)((u2 < HID) ? &w1T[u2 * 128] : &w3T[(u2 - HID) * 128]);
        bool v3 = u3 < 2 * HID;
        const float4* pc = (const float4*)(v3 ? &w3T[(u3 - HID) * 128] : &w3T[0]);
        float a0 = 0, a1 = 0, b0 = 0, b1 = 0, c0 = 0, c1 = 0;
        #pragma unroll
        for (int i = 0; i < 32; ++i) {
            float4 hh = h24[i];
            float4 wa = pa[i];
            a0 += hh.x * wa.x + hh.y * wa.y;
            a1 += hh.z * wa.z + hh.w * wa.w;
            float4 wb = pb[i];
            b0 += hh.x * wb.x + hh.y * wb.y;
            b1 += hh.z * wb.z + hh.w * wb.w;
            float4 wc = pc[i];
            c0 += hh.x * wc.x + hh.y * wc.y;
            c1 += hh.z * wc.z + hh.w * wc.w;
        }
        afA[u1] = a0 + a1;
        if (u2 < HID) afA[u2] = b0 + b1;
        else afB[u2 - HID] = b0 + b1;
        if (v3) afB[u3 - HID] = c0 + c1;
    }
    __syncthreads();
    for (int c2 = t; c2 < HIDP; c2 += 256) {
        if (c2 < HID) {
            float a = afA[c2];
            af[c2] = (a / (1.0f + __expf(-a))) * afB[c2];
        } else {
            af[c2] = 0.f;
        }
    }
    __syncthreads();

    // FFN2: w2T padded rows; thread (c, k-half); 43 float4
    {
        int klo = half * 172;
        const float4* wp = (const float4*)&w2T[col * HIDP + klo];
        const float4* ap = (const float4*)&af[klo];
        float a0 = 0, a1 = 0, a2 = 0, a3 = 0;
        #pragma unroll
        for (int i = 0; i < 43; ++i) {
            float4 ww = wp[i];
            float4 aa = ap[i];
            a0 += aa.x * ww.x;
            a1 += aa.y * ww.y;
            a2 += aa.z * ww.z;
            a3 += aa.w * ww.w;
        }
        part[half][col] = (a0 + a1) + (a2 + a3);
    }
    __syncthreads();
    float x2 = 0.f;
    if (t < 128) {
        x2 = xn + part[0][t] + part[1][t];
        if (MODE == 0) x[s * D + t] = x2;
    }
    float ss3 = block_sum256((t < 128) ? x2 * x2 : 0.f, scr);
    float r3 = 1.0f / sqrtf(ss3 * (1.0f / D) + EPS);

    if constexpr (MODE == 0) {
        if (t < 128) h2[t] = x2 * r3 * n1w[t];
        __syncthreads();
        // q/k: 32 float4 each; v: 16 float4 (d-half split)
        float qk;
        {
            const float4* wp = (const float4*)((t < 128) ? &wqT[col * 128] : &wkT[col * 128]);
            float a0 = 0, a1 = 0;
            #pragma unroll
            for (int i = 0; i < 32; ++i) {
                float4 hh = h24[i];
                float4 ww = wp[i];
                a0 += hh.x * ww.x + hh.y * ww.y;
                a1 += hh.z * ww.z + hh.w * ww.w;
            }
            qk = a0 + a1;
        }
        {
            int dlo = half * 64;
            const float4* wp = (const float4*)&wvT[col * 128 + dlo];
            float a0 = 0, a1 = 0;
            #pragma unroll
            for (int i = 0; i < 16; ++i) {
                float4 hh = h24[dlo / 4 + i];
                float4 ww = wp[i];
                a0 += hh.x * ww.x + hh.y * ww.y;
                a1 += hh.z * ww.z + hh.w * ww.w;
            }
            part[half][col] = a0 + a1;
        }
        if (t < 128) qrow[col] = qk;
        else krow[col] = qk;
        __syncthreads();
        if (t < 128) {
            vto[t * SEQ + s] = part[0][t] + part[1][t];
            int c = t & (HD - 1);
            int mm = c >> 1;
            float fr = (float)s * expf(-(float)mm * 1.15129254649702283e+00f);
            float cs = cosf(fr), sn = sinf(fr);
            int base = t & ~1;
            float qe = qrow[base], qod = qrow[base + 1];
            float ke = krow[base], kod = krow[base + 1];
            qo[s * D + t] = (c & 1) ? (qe * sn + qod * cs) : (qe * cs - qod * sn);
            ko[s * D + t] = (c & 1) ? (ke * sn + kod * cs) : (ke * cs - kod * sn);
        }
    } else {
        float y = (t < 128) ? x2 * r3 * fw[t] : 0.f;
        float nn = block_sum256(y * y, scr);
        if (t < 128) xng[t * SEQ + s] = y / sqrtf(nn);
    }
}

// K4: logits[s,v] = clip(mean_d(xn[s,d] <= vn[v,d] ? 1 : vn[v,d]))
__global__ __launch_bounds__(256) void k_logits(const float* __restrict__ xng,
                                                const float* __restrict__ w_raw,
                                                float* __restrict__ out) {
    __shared__ float xs[D * 64];
    __shared__ float vs[D * 32];
    __shared__ float nred[256];
    __shared__ float invn_s[32];
    int t = threadIdx.x;
    int sbase = (blockIdx.x & 1) * 64;
    int vbase = (blockIdx.x >> 1) * 32;
    for (int i = t; i < D * 64; i += 256) {
        int d = i >> 6, s2 = i & 63;
        xs[i] = xng[d * SEQ + sbase + s2];
    }
    for (int i = t; i < D * 32; i += 256) {
        int d = i >> 5, jj = i & 31;
        vs[i] = sigm(w_raw[d * V + vbase + jj]);
    }
    __syncthreads();
    {
        int colc = t & 31, dp = t >> 5;
        float p = 0.f;
        for (int u = 0; u < 16; ++u) {
            float vv = vs[(dp * 16 + u) * 32 + colc];
            p += vv * vv;
        }
        nred[t] = p;
    }
    __syncthreads();
    if (t < 32) {
        float sum = 0.f;
        for (int u = 0; u < 8; ++u) sum += nred[u * 32 + t];
        invn_s[t] = 1.0f / sqrtf(sum);
    }
    __syncthreads();
    for (int i = t; i < D * 32; i += 256) vs[i] *= invn_s[i & 31];
    __syncthreads();
    int vg = t & 15;
    int sg = t >> 4;
    float acc[4][2] = {};
    for (int d = 0; d < D; ++d) {
        float4 xq = *(const float4*)&xs[d * 64 + sg * 4];
        float2 vq = *(const float2*)&vs[d * 32 + vg * 2];
        acc[0][0] += (xq.x <= vq.x) ? 1.0f : vq.x;
        acc[0][1] += (xq.x <= vq.y) ? 1.0f : vq.y;
        acc[1][0] += (xq.y <= vq.x) ? 1.0f : vq.x;
        acc[1][1] += (xq.y <= vq.y) ? 1.0f : vq.y;
        acc[2][0] += (xq.z <= vq.x) ? 1.0f : vq.x;
        acc[2][1] += (xq.z <= vq.y) ? 1.0f : vq.y;
        acc[3][0] += (xq.w <= vq.x) ? 1.0f : vq.x;
        acc[3][1] += (xq.w <= vq.y) ? 1.0f : vq.y;
    }
    const float inv128 = 1.0f / 128.0f;
    #pragma unroll
    for (int si = 0; si < 4; ++si) {
        int s = sbase + sg * 4 + si;
        float2 ov;
        ov.x = fminf(fmaxf(acc[si][0] * inv128, 1e-6f), 1.0f - 1e-6f);
        ov.y = fminf(fmaxf(acc[si][1] * inv128, 1e-6f), 1.0f - 1e-6f);
        *(float2*)&out[s * V + vbase + vg * 2] = ov;
    }
}

extern "C" void kernel_launch(void* const* d_in, const int* in_sizes, int n_in,
                              void* d_out, int out_size, void* d_ws, size_t ws_size,
                              hipStream_t stream) {
    const int* idx = (const int*)d_in[0];
    const float* w_raw = (const float*)d_in[1];
    const float* n1w = (const float*)d_in[2];
    const float* n2w = (const float*)d_in[3];
    const float* wq = (const float*)d_in[4];
    const float* wk = (const float*)d_in[5];
    const float* wv = (const float*)d_in[6];
    const float* wo = (const float*)d_in[7];
    const float* w1 = (const float*)d_in[8];
    const float* w3 = (const float*)d_in[9];
    const float* w2 = (const float*)d_in[10];
    const float* fnw = (const float*)d_in[11];
    float* out = (float*)d_out;
    float* ws = (float*)d_ws;

    float* x    = ws;              // 16384
    float* q1   = ws + 16384;
    float* k1   = ws + 32768;
    float* v1t  = ws + 49152;      // V^T [D][SEQ]
    float* q2   = ws + 65536;
    float* k2   = ws + 81920;
    float* v2t  = ws + 98304;
    float* xng  = ws + 114688;
    float* sink = ws + 131072;
    float* wqT  = ws + 131104;     // 2 x 16384
    float* wkT  = ws + 163872;
    float* wvT  = ws + 196640;
    float* woT  = ws + 229408;
    float* w1T  = ws + 262176;     // 2 x 43648
    float* w3T  = ws + 349472;
    float* w2T  = ws + 436768;     // 2 x 44032 (rows padded to 344)

    k_embed_qkv<<<dim3(SEQ + 256), dim3(256), 0, stream>>>(
        idx, w_raw, wq, wk, wv, wo, w1, w3, w2, n1w, x, q1, k1, v1t,
        wqT, wkT, wvT, woT, w1T, w3T, w2T, sink);
    k_layer<0><<<dim3(SEQ), dim3(256), 0, stream>>>(
        q1, k1, v1t, x, woT, n2w, w1T, w3T, w2T,
        wqT + 16384, wkT + 16384, wvT + 16384, n1w + D, q2, k2, v2t,
        (const float*)nullptr, (float*)nullptr);
    k_layer<1><<<dim3(SEQ), dim3(256), 0, stream>>>(
        q2, k2, v2t, x, woT + 16384, n2w + D, w1T + 43648, w3T + 43648,
        w2T + 44032, (const float*)nullptr, (const float*)nullptr,
        (const float*)nullptr, (const float*)nullptr, (float*)nullptr,
        (float*)nullptr, (float*)nullptr, fnw, xng);
    k_logits<<<dim3(512), dim3(256), 0, stream>>>(xng, w_raw, out);
}